// Round 10
// baseline (1319.359 us; speedup 1.0000x reference)
//
#include <hip/hip_runtime.h>
#include <math.h>

#define Bsz 256
#define Tsz 128
#define Esz 256
#define Hsz 256
#define Gsz 1024   // 4*H
#define Osz 1024
#define KFC 32768  // T*H
#define KSPLIT 32
#define NBI 16     // batch groups (16 rows each)
#define NHJ 16     // h-col groups (16 cols each)
#define PPAD 76    // Pp row pad (reads ~2-way instead of 4-way at 68)

__device__ __forceinline__ float sigmoidf_(float x) { return 1.0f / (1.0f + expf(-x)); }

// out[k*N + n] = in[n*K + k]   (transpose [N,K] -> [K,N])
__global__ void transpose_kn(const float* __restrict__ in, float* __restrict__ out, int N, int K) {
    int i = blockIdx.x * blockDim.x + threadIdx.x;
    if (i >= N * K) return;
    int k = i / N;
    int n = i - k * N;
    out[i] = in[n * K + k];
}

// ---------------------------------------------------------------------------
// 128x128-tile fp32 GEMM: C = A[M,K]*W[N,K]^T. 256 thr, 8x8 acc, k-chunk 16,
// register prefetch. BIAS=1: +bias, direct store. BIAS=0: blockIdx.z K-slice.
// ---------------------------------------------------------------------------
template <int BIAS>
__global__ __launch_bounds__(256, 2) void gemm128(const float* __restrict__ A, int lda,
                                                  const float* __restrict__ W, int ldw,
                                                  const float* __restrict__ bih,
                                                  const float* __restrict__ bhh,
                                                  float* __restrict__ C, int ldc,
                                                  int klen) {
    __shared__ float As[16][132];
    __shared__ float Bs[16][132];
    int tid = threadIdx.x;
    int tm = tid & 15, tn = tid >> 4;
    int lrow = tid >> 1, lkc = (tid & 1) * 8;
    int kbase = blockIdx.z * klen;
    const float* Ap = A + (size_t)(blockIdx.x * 128 + lrow) * lda + kbase + lkc;
    const float* Wp = W + (size_t)(blockIdx.y * 128 + lrow) * ldw + kbase + lkc;
    float4 pa0, pa1, pb0, pb1;
    pa0 = *(const float4*)(Ap);     pa1 = *(const float4*)(Ap + 4);
    pb0 = *(const float4*)(Wp);     pb1 = *(const float4*)(Wp + 4);
    float acc[8][8] = {};
    int nc = klen >> 4;
    for (int c = 0; c < nc; ++c) {
        __syncthreads();
        As[lkc + 0][lrow] = pa0.x; As[lkc + 1][lrow] = pa0.y; As[lkc + 2][lrow] = pa0.z; As[lkc + 3][lrow] = pa0.w;
        As[lkc + 4][lrow] = pa1.x; As[lkc + 5][lrow] = pa1.y; As[lkc + 6][lrow] = pa1.z; As[lkc + 7][lrow] = pa1.w;
        Bs[lkc + 0][lrow] = pb0.x; Bs[lkc + 1][lrow] = pb0.y; Bs[lkc + 2][lrow] = pb0.z; Bs[lkc + 3][lrow] = pb0.w;
        Bs[lkc + 4][lrow] = pb1.x; Bs[lkc + 5][lrow] = pb1.y; Bs[lkc + 6][lrow] = pb1.z; Bs[lkc + 7][lrow] = pb1.w;
        __syncthreads();
        if (c + 1 < nc) {
            int off = (c + 1) * 16;
            pa0 = *(const float4*)(Ap + off);     pa1 = *(const float4*)(Ap + off + 4);
            pb0 = *(const float4*)(Wp + off);     pb1 = *(const float4*)(Wp + off + 4);
        }
#pragma unroll
        for (int kk = 0; kk < 16; ++kk) {
            float4 a0 = *(const float4*)&As[kk][tm * 8];
            float4 a1 = *(const float4*)&As[kk][tm * 8 + 4];
            float4 b0 = *(const float4*)&Bs[kk][tn * 8];
            float4 b1 = *(const float4*)&Bs[kk][tn * 8 + 4];
            float ar[8] = {a0.x, a0.y, a0.z, a0.w, a1.x, a1.y, a1.z, a1.w};
            float br[8] = {b0.x, b0.y, b0.z, b0.w, b1.x, b1.y, b1.z, b1.w};
#pragma unroll
            for (int i = 0; i < 8; ++i)
#pragma unroll
                for (int j = 0; j < 8; ++j) acc[i][j] += ar[i] * br[j];
        }
    }
    int row0 = blockIdx.x * 128 + tm * 8;
    int col0 = blockIdx.y * 128 + tn * 8;
    float* Cout = C + (BIAS ? 0 : (size_t)blockIdx.z * Bsz * Osz);
    float bias[8];
#pragma unroll
    for (int j = 0; j < 8; ++j) bias[j] = BIAS ? (bih[col0 + j] + bhh[col0 + j]) : 0.f;
#pragma unroll
    for (int i = 0; i < 8; ++i) {
        float4 o0, o1;
        o0.x = acc[i][0] + bias[0]; o0.y = acc[i][1] + bias[1];
        o0.z = acc[i][2] + bias[2]; o0.w = acc[i][3] + bias[3];
        o1.x = acc[i][4] + bias[4]; o1.y = acc[i][5] + bias[5];
        o1.z = acc[i][6] + bias[6]; o1.w = acc[i][7] + bias[7];
        *(float4*)&Cout[(size_t)(row0 + i) * ldc + col0] = o0;
        *(float4*)&Cout[(size_t)(row0 + i) * ldc + col0 + 4] = o1;
    }
}

// out[m][n] = b_fc[n] + sum_ks P[ks][m][n]
__global__ void reduce_out(const float* __restrict__ P, const float* __restrict__ bfc,
                           float* __restrict__ out) {
    int i = blockIdx.x * blockDim.x + threadIdx.x;
    if (i >= Bsz * Osz) return;
    float s = bfc[i & (Osz - 1)];
#pragma unroll
    for (int ks = 0; ks < KSPLIT; ++ks) s += P[(size_t)ks * Bsz * Osz + i];
    out[i] = s;
}

// ---------------------------------------------------------------------------
// Cooperative LSTM scan v3. Grid (NHJ,NBI)=256 WGs x 1024 thr, 1 WG/CU
// (96 KB LDS -> exclusive residency -> all 256 WGs co-resident).
// Changes vs v2 (round 6, 594 us, sync ~4K cyc/step of 11.1K):
//  * flag-based release: writer drains h stores at __syncthreads (vmcnt(0)),
//    then tid0 fire-and-forget relaxed-agent store flag[bi][hj]=t+1 into a
//    64B-padded slot. Readers: 16 threads poll 16 flags in PARALLEL.
//    Removes fetch_add round-trip + 16-WG same-cacheline RMW serialization.
//    Ordering stays structural/temporal: h acked BEFORE flag issued;
//    reader loads issued AFTER flag observed; all h traffic L2-bypass.
//  * stage loads widened to 2x b64 relaxed-agent loads.
//  * Pp pad 68->76: reduce-read bank conflicts ~4-way -> ~2-way.
// ---------------------------------------------------------------------------
__global__ __launch_bounds__(1024) void lstm_scan_coop3(
    const float* __restrict__ xg,    // [B*T][1024] (bias pre-added)
    const float* __restrict__ whhT,  // [256][1024]
    float* __restrict__ hs,          // [B][KFC]
    float* hbuf,                     // [NBI][2][4096] zeroed
    unsigned int* flags)             // [NBI][NHJ][16] zeroed (64B-padded slots)
{
    const int hj = blockIdx.x, bi = blockIdx.y;
    const int tid = threadIdx.x;
    __shared__ float HT[256][16];        // 16 KB: HT[k][r]
    __shared__ float Pp[16][16][PPAD];   // 77.8 KB partials
    __shared__ float gbuf[4][16][16];    // 4 KB activated gates

    const int ks   = tid >> 6;        // k-slice (wave) 0..15, 16 k each
    const int rgrp = (tid >> 4) & 3;  // 4-row group
    const int cgrp = tid & 15;        // 16 col-quads (gate = cgrp>>2, quad = cgrp&3)
    // one-time: this thread's 16x4 w_hh slice into registers
    const int colbase = (cgrp >> 2) * 256 + hj * 16 + (cgrp & 3) * 4;
    float4 w[16];
#pragma unroll
    for (int kk = 0; kk < 16; ++kk)
        w[kk] = *(const float4*)&whhT[(size_t)(ks * 16 + kk) * Gsz + colbase];

    // reduce-phase mapping: thread = (gate gq, row rq, col hq)
    const int gq = tid >> 8, rq = (tid >> 4) & 15, hq = tid & 15;
    // update-phase mapping (tid<256)
    const int r_a = tid >> 4, hc_a = tid & 15;
    float c_state = 0.f;
    float* hb = hbuf + (size_t)bi * 8192;
    unsigned int* fl = flags + (size_t)bi * NHJ * 16;  // fl[g*16] = flag of WG (bi,g)

    for (int t = 0; t < Tsz; ++t) {
        const int p = t & 1;
        // ---- acquire: 16 parallel pollers, one flag each (t=0 trivially passes)
        if (t > 0 && tid < NHJ) {
            unsigned target = (unsigned)t;
            long guard = 0;
            while (__hip_atomic_load(fl + tid * 16, __ATOMIC_RELAXED, __HIP_MEMORY_SCOPE_AGENT) < target) {
                if (++guard > (1L << 22)) break;  // deadlock escape (never hit when resident)
            }
        }
        __syncthreads();  // B1: all flags observed
        // ---- stage h_{t-1} from IF into LDS (L2-bypass, 2x b64 per thread)
        {
            const unsigned long long* src = (const unsigned long long*)(hb + (size_t)p * 4096);
            unsigned long long* dst = (unsigned long long*)&HT[0][0];
            unsigned long long v0 = __hip_atomic_load(src + tid,        __ATOMIC_RELAXED, __HIP_MEMORY_SCOPE_AGENT);
            unsigned long long v1 = __hip_atomic_load(src + tid + 1024, __ATOMIC_RELAXED, __HIP_MEMORY_SCOPE_AGENT);
            dst[tid] = v0;
            dst[tid + 1024] = v1;
        }
        // prefetch this thread's xg gate value (consumed in reduce phase)
        float xgv = xg[((size_t)(bi * 16 + rq) * Tsz + t) * Gsz + gq * 256 + hj * 16 + hq];
        __syncthreads();  // B2: HT ready
        // ---- GEMM: acc[4r][4c] over this wave's 16-k slice, w from registers
        float acc[4][4] = {};
#pragma unroll
        for (int kk = 0; kk < 16; ++kk) {
            float4 hv = *(const float4*)&HT[ks * 16 + kk][rgrp * 4];
            float hr[4] = {hv.x, hv.y, hv.z, hv.w};
            float wr[4] = {w[kk].x, w[kk].y, w[kk].z, w[kk].w};
#pragma unroll
            for (int i = 0; i < 4; ++i)
#pragma unroll
                for (int j = 0; j < 4; ++j) acc[i][j] += hr[i] * wr[j];
        }
#pragma unroll
        for (int i = 0; i < 4; ++i)
            *(float4*)&Pp[ks][rgrp * 4 + i][cgrp * 4] =
                make_float4(acc[i][0], acc[i][1], acc[i][2], acc[i][3]);
        __syncthreads();  // B3: partials ready
        // ---- parallel reduce + activation: each thread owns ONE gate value
        {
            float s = 0.f;
#pragma unroll
            for (int sl = 0; sl < 16; ++sl) s += Pp[sl][rq][gq * 16 + hq];
            s += xgv;
            s = (gq == 2) ? tanhf(s) : sigmoidf_(s);   // gq wave-uniform
            gbuf[gq][rq][hq] = s;
        }
        __syncthreads();  // B4: gates ready
        // ---- state update (tid<256)
        if (tid < 256) {
            float gi = gbuf[0][r_a][hc_a];
            float gf = gbuf[1][r_a][hc_a];
            float gg = gbuf[2][r_a][hc_a];
            float go = gbuf[3][r_a][hc_a];
            c_state = gf * c_state + gi * gg;
            float hval = go * tanhf(c_state);
            hs[(size_t)(bi * 16 + r_a) * KFC + t * Hsz + hj * 16 + hc_a] = hval;
            // write-through store to IF (visible to agent readers, no cache maint)
            __hip_atomic_store((unsigned int*)hb + (size_t)(p ^ 1) * 4096 + (hj * 16 + hc_a) * 16 + r_a,
                               __float_as_uint(hval),
                               __ATOMIC_RELAXED, __HIP_MEMORY_SCOPE_AGENT);
        }
        __syncthreads();  // B5: vmcnt(0) drain -> all h stores acked at IF
        // ---- release: fire-and-forget flag store (lands in background)
        if (tid == 0 && t < Tsz - 1) {
            __hip_atomic_store(fl + hj * 16, (unsigned)(t + 1),
                               __ATOMIC_RELAXED, __HIP_MEMORY_SCOPE_AGENT);
        }
    }
}

// ---- small-ws fallback path (round-2 design, correct but slower) ----------
__device__ __forceinline__ void matvec_acc(const float* __restrict__ WT, const float4* HV, int len,
                                           int col0, int col1, float a0[4], float a1[4]) {
    float wa0[4], wa1[4], wb0[4], wb1[4];
#pragma unroll
    for (int q = 0; q < 4; ++q) { wa0[q] = WT[q * Gsz + col0]; wa1[q] = WT[q * Gsz + col1]; }
    for (int k = 0; k < len; k += 8) {
#pragma unroll
        for (int q = 0; q < 4; ++q) {
            int kk = (k + 4 + q) & (len - 1);
            wb0[q] = WT[kk * Gsz + col0]; wb1[q] = WT[kk * Gsz + col1];
        }
#pragma unroll
        for (int q = 0; q < 4; ++q) {
            float4 hq = HV[k + q];
            a0[0] += wa0[q] * hq.x; a0[1] += wa0[q] * hq.y; a0[2] += wa0[q] * hq.z; a0[3] += wa0[q] * hq.w;
            a1[0] += wa1[q] * hq.x; a1[1] += wa1[q] * hq.y; a1[2] += wa1[q] * hq.z; a1[3] += wa1[q] * hq.w;
        }
#pragma unroll
        for (int q = 0; q < 4; ++q) {
            int kk = (k + 8 + q) & (len - 1);
            wa0[q] = WT[kk * Gsz + col0]; wa1[q] = WT[kk * Gsz + col1];
        }
#pragma unroll
        for (int q = 0; q < 4; ++q) {
            float4 hq = HV[k + 4 + q];
            a0[0] += wb0[q] * hq.x; a0[1] += wb0[q] * hq.y; a0[2] += wb0[q] * hq.z; a0[3] += wb0[q] * hq.w;
            a1[0] += wb1[q] * hq.x; a1[1] += wb1[q] * hq.y; a1[2] += wb1[q] * hq.z; a1[3] += wb1[q] * hq.w;
        }
    }
}

template <int XGF>
__global__ __launch_bounds__(512) void lstm_scan(const float* __restrict__ xgin,
                                                 const float* __restrict__ whhT,
                                                 const float* __restrict__ wihT,
                                                 const float* __restrict__ bih,
                                                 const float* __restrict__ bhh,
                                                 float* __restrict__ hs) {
    int j = threadIdx.x;
    int b0 = blockIdx.x * 4;
    int col0 = j, col1 = j + 512;
    __shared__ float4 h4[Hsz];
    __shared__ float4 x4[Esz];
    __shared__ float fo[2][4][Hsz];
    float c[4] = {0.f, 0.f, 0.f, 0.f};
    float bias0 = 0.f, bias1 = 0.f;
    if (XGF) { bias0 = bih[col0] + bhh[col0]; bias1 = bih[col1] + bhh[col1]; }
    if (j < Hsz) h4[j] = make_float4(0.f, 0.f, 0.f, 0.f);
    __syncthreads();
    for (int t = 0; t < Tsz; ++t) {
        float a0[4], a1[4];
        if (XGF) {
#pragma unroll
            for (int r = 0; r < 4; ++r) { a0[r] = bias0; a1[r] = bias1; }
            if (j < Esz) {
                float4 v;
                v.x = xgin[((size_t)(b0 + 0) * Tsz + t) * Esz + j];
                v.y = xgin[((size_t)(b0 + 1) * Tsz + t) * Esz + j];
                v.z = xgin[((size_t)(b0 + 2) * Tsz + t) * Esz + j];
                v.w = xgin[((size_t)(b0 + 3) * Tsz + t) * Esz + j];
                x4[j] = v;
            }
            __syncthreads();
            matvec_acc(wihT, x4, Esz, col0, col1, a0, a1);
        } else {
#pragma unroll
            for (int r = 0; r < 4; ++r) {
                a0[r] = xgin[((size_t)(b0 + r) * Tsz + t) * Gsz + col0];
                a1[r] = xgin[((size_t)(b0 + r) * Tsz + t) * Gsz + col1];
            }
        }
        matvec_acc(whhT, h4, Hsz, col0, col1, a0, a1);
        if (j < Hsz) {
#pragma unroll
            for (int r = 0; r < 4; ++r) { a0[r] = sigmoidf_(a0[r]); a1[r] = tanhf(a1[r]); }
        } else {
#pragma unroll
            for (int r = 0; r < 4; ++r) {
                fo[0][r][j - Hsz] = sigmoidf_(a0[r]);
                fo[1][r][j - Hsz] = sigmoidf_(a1[r]);
            }
        }
        __syncthreads();
        if (j < Hsz) {
            float hv[4];
#pragma unroll
            for (int r = 0; r < 4; ++r) {
                float f = fo[0][r][j], o = fo[1][r][j];
                c[r] = f * c[r] + a0[r] * a1[r];
                hv[r] = o * tanhf(c[r]);
                hs[(size_t)(b0 + r) * KFC + t * Hsz + j] = hv[r];
            }
            h4[j] = make_float4(hv[0], hv[1], hv[2], hv[3]);
        }
        __syncthreads();
    }
}

extern "C" void kernel_launch(void* const* d_in, const int* in_sizes, int n_in,
                              void* d_out, int out_size, void* d_ws, size_t ws_size,
                              hipStream_t stream) {
    const float* x    = (const float*)d_in[0];
    const float* w_ih = (const float*)d_in[1];
    const float* w_hh = (const float*)d_in[2];
    const float* b_ih = (const float*)d_in[3];
    const float* b_hh = (const float*)d_in[4];
    const float* w_fc = (const float*)d_in[5];
    const float* b_fc = (const float*)d_in[6];
    float* out = (float*)d_out;
    char* ws = (char*)d_ws;

    const size_t XG_BYTES = (size_t)Bsz * Tsz * Gsz * 4;    // 128 MB
    const size_t WT_BYTES = (size_t)Esz * Gsz * 4;          // 1 MB
    const size_t HS_BYTES = (size_t)Bsz * KFC * 4;          // 32 MB
    const size_t P_BYTES  = (size_t)KSPLIT * Bsz * Osz * 4; // 32 MB
    const size_t HB_BYTES = (size_t)NBI * 2 * 4096 * 4;     // 512 KB
    const size_t FL_BYTES = (size_t)NBI * NHJ * 16 * 4;     // 16 KB
    bool fast = ws_size >= XG_BYTES + WT_BYTES + HS_BYTES + P_BYTES + HB_BYTES + FL_BYTES;

    const int KLEN = KFC / KSPLIT;  // 1024

    if (fast) {
        float* xg   = (float*)(ws);
        float* whhT = (float*)(ws + XG_BYTES);
        float* hsb  = (float*)(ws + XG_BYTES + WT_BYTES);
        float* part = (float*)(ws + XG_BYTES + WT_BYTES + HS_BYTES);
        float* hbuf = (float*)(ws + XG_BYTES + WT_BYTES + HS_BYTES + P_BYTES);
        unsigned int* flags = (unsigned int*)(ws + XG_BYTES + WT_BYTES + HS_BYTES + P_BYTES + HB_BYTES);
        hipMemsetAsync(hbuf, 0, HB_BYTES + FL_BYTES, stream);
        transpose_kn<<<(Esz * Gsz + 255) / 256, 256, 0, stream>>>(w_hh, whhT, Gsz, Esz);
        gemm128<1><<<dim3(Bsz * Tsz / 128, Gsz / 128, 1), 256, 0, stream>>>(
            x, Esz, w_ih, Esz, b_ih, b_hh, xg, Gsz, Esz);
        lstm_scan_coop3<<<dim3(NHJ, NBI), 1024, 0, stream>>>(xg, whhT, hsb, hbuf, flags);
        gemm128<0><<<dim3(Bsz / 128, Osz / 128, KSPLIT), 256, 0, stream>>>(
            hsb, KFC, w_fc, KFC, nullptr, nullptr, part, Osz, KLEN);
        reduce_out<<<(Bsz * Osz + 255) / 256, 256, 0, stream>>>(part, b_fc, out);
    } else {
        float* whhT = (float*)(ws);
        float* wihT = (float*)(ws + WT_BYTES);
        float* hsb  = (float*)(ws + 2 * WT_BYTES);
        float* part = (float*)(ws + 2 * WT_BYTES + HS_BYTES);
        transpose_kn<<<(Esz * Gsz + 255) / 256, 256, 0, stream>>>(w_hh, whhT, Gsz, Esz);
        transpose_kn<<<(Esz * Gsz + 255) / 256, 256, 0, stream>>>(w_ih, wihT, Gsz, Esz);
        lstm_scan<1><<<Bsz / 4, 512, 0, stream>>>(x, whhT, wihT, b_ih, b_hh, hsb);
        gemm128<0><<<dim3(Bsz / 128, Osz / 128, KSPLIT), 256, 0, stream>>>(
            hsb, KFC, w_fc, KFC, nullptr, nullptr, part, Osz, KLEN);
        reduce_out<<<(Bsz * Osz + 255) / 256, 256, 0, stream>>>(part, b_fc, out);
    }
}